// Round 1
// baseline (269.485 us; speedup 1.0000x reference)
//
#include <hip/hip_runtime.h>

// Windowed attention smoothing, fully fused, LDS-free.
// rows = 200000, RANK = 64, WINDOW = 11.
// Layout: one wave (64 lanes) per row; each wave walks 16 consecutive rows.
// lane c owns column c throughout (var1[c], A[.][c], out[.][c]).

constexpr int RANK           = 64;
constexpr int WINDOW         = 11;
constexpr int PAD            = 5;
constexpr int ROWS_PER_WAVE  = 16;
constexpr int BLOCK          = 256;
constexpr int WAVES_PER_BLK  = BLOCK / 64;

// ---- DPP cross-lane sum (VALU pipe, no LDS/DS traffic) ----
template <int Ctrl, int RowMask, bool BoundCtrl>
__device__ __forceinline__ float dpp_add(float x) {
    int t = __builtin_amdgcn_update_dpp(0, __float_as_int(x), Ctrl, RowMask, 0xf,
                                        BoundCtrl);
    return x + __int_as_float(t);
}

// Classic GCN 64-lane sum; result valid in lane 63.
__device__ __forceinline__ float wave_sum_lane63(float x) {
    x = dpp_add<0x111, 0xf, true >(x);  // row_shr:1
    x = dpp_add<0x112, 0xf, true >(x);  // row_shr:2
    x = dpp_add<0x114, 0xf, true >(x);  // row_shr:4
    x = dpp_add<0x118, 0xf, true >(x);  // row_shr:8  -> lane15/31/47/63 = row sums
    x = dpp_add<0x142, 0xa, false>(x);  // row_bcast:15 -> rows 1,3
    x = dpp_add<0x143, 0xc, false>(x);  // row_bcast:31 -> rows 2,3; lane63 = total
    return x;
}

__device__ __forceinline__ float fast_tanh(float x) {
    // tanh(x) = 1 - 2/(exp(2x)+1); saturates correctly at +-inf.
    return 1.0f - 2.0f / (1.0f + __expf(2.0f * x));
}

__global__ __launch_bounds__(BLOCK, 4) void attn_win_kernel(
    const float* __restrict__ A,   // (rows, 64)
    const float* __restrict__ W,   // (64, 64)  row-major (out,in)
    const float* __restrict__ b,   // (64,)
    float* __restrict__ out,       // (rows, 64)
    int rows)
{
    const int lane = threadIdx.x & 63;
    int wid = threadIdx.x >> 6;
    wid = __builtin_amdgcn_readfirstlane(wid);           // provably uniform
    const int wave_global = blockIdx.x * WAVES_PER_BLK + wid;
    const int r0 = wave_global * ROWS_PER_WAVE;
    if (r0 >= rows) return;

    // lane c caches W[c][0..63] in 16 float4 regs (64 VGPRs), reused for 16 rows.
    float4 wreg[16];
    {
        const float4* Wrow = (const float4*)(W + lane * RANK);
        #pragma unroll
        for (int i = 0; i < 16; i++) wreg[i] = Wrow[i];
    }
    const float bias = b[lane];

    for (int rr = 0; rr < ROWS_PER_WAVE; rr++) {
        const int r = r0 + rr;
        if (r >= rows) break;                            // wave-uniform guard

        // ---- P1: var1[c] = tanh(dot(A[r], W[c]) + b[c]) ----
        // A-row address is wave-uniform -> scalar loads; FMA w/ SGPR operand.
        const float* Arow = A + (size_t)r * RANK;
        float acc = bias;
        #pragma unroll
        for (int i = 0; i < 16; i++) {
            const float4 av = *(const float4*)(Arow + 4 * i);
            acc = fmaf(av.x, wreg[i].x, acc);
            acc = fmaf(av.y, wreg[i].y, acc);
            acc = fmaf(av.z, wreg[i].z, acc);
            acc = fmaf(av.w, wreg[i].w, acc);
        }
        const float v1 = fast_tanh(acc);

        // ---- P2: s_w = dot(A[r-5+w], var1), w = 0..10 ----
        float aw[WINDOW];   // window A values stay in regs for P4 reuse
        float sc[WINDOW];   // scores (uniform after readlane -> SGPRs)
        #pragma unroll
        for (int w = 0; w < WINDOW; w++) {
            const int rp = r - PAD + w;                  // wave-uniform
            float a = 0.0f;
            if (rp >= 0 && rp < rows) a = A[(size_t)rp * RANK + lane];
            aw[w] = a;                                   // zero pad rows -> score 0
            const float red = wave_sum_lane63(a * v1);
            sc[w] = __int_as_float(
                __builtin_amdgcn_readlane(__float_as_int(red), 63));
        }

        // ---- P3: softmax over window (scale 1/sqrt(64) = 0.125) ----
        float m = sc[0];
        #pragma unroll
        for (int w = 1; w < WINDOW; w++) m = fmaxf(m, sc[w]);
        float p[WINDOW];
        float denom = 0.0f;
        #pragma unroll
        for (int w = 0; w < WINDOW; w++) {
            p[w] = __expf((sc[w] - m) * 0.125f);
            denom += p[w];
        }
        const float rden = __fdividef(1.0f, denom);

        // ---- P4: out[r][c] = sum_w p_w * A[r-5+w][c] ----
        float o = 0.0f;
        #pragma unroll
        for (int w = 0; w < WINDOW; w++) o = fmaf(p[w], aw[w], o);
        out[(size_t)r * RANK + lane] = o * rden;
    }
}

extern "C" void kernel_launch(void* const* d_in, const int* in_sizes, int n_in,
                              void* d_out, int out_size, void* d_ws, size_t ws_size,
                              hipStream_t stream) {
    const float* A = (const float*)d_in[0];   // time_factor (rows, 64)
    const float* W = (const float*)d_in[1];   // (64, 64)
    const float* b = (const float*)d_in[2];   // (64,)
    float* out = (float*)d_out;

    const int rows = in_sizes[0] / RANK;
    const int waves = (rows + ROWS_PER_WAVE - 1) / ROWS_PER_WAVE;
    const int blocks = (waves + WAVES_PER_BLK - 1) / WAVES_PER_BLK;

    hipLaunchKernelGGL(attn_win_kernel, dim3(blocks), dim3(BLOCK), 0, stream,
                       A, W, b, out, rows);
}

// Round 2
// 167.821 us; speedup vs baseline: 1.6058x; 1.6058x over previous
//
#include <hip/hip_runtime.h>

// Windowed attention smoothing via MFMA, rows=200000, RANK=64, WINDOW=11.
// Block = 256 thr (4 waves), 64 rows/block, 16 rows/wave.
// Per wave: stage bf16 A-window (26 rows) -> LDS; M1 (V1=tanh(A@W^T+b)) and
// M2 (banded scores) via mfma_f32_16x16x32_bf16; softmax on 16 columns with
// LDS-broadcast reads; P4 weighted window sum in VALU with rolling registers
// and static v_readlane prob broadcast.

constexpr int RANK   = 64;
constexpr int WINDOW = 11;
constexpr int PAD    = 5;
constexpr int TILE   = 16;   // rows per wave
constexpr int BLOCK  = 256;  // 4 waves
constexpr int TR     = 64;   // rows per block

typedef short short8   __attribute__((ext_vector_type(8)));
typedef float float4v  __attribute__((ext_vector_type(4)));

// LDS strides in ELEMENTS. bf16 stride 72 -> 144B rows (16B aligned, odd
// dword multiple 36 -> conflict-friendly). Sc stride 17 f32 breaks pow2.
constexpr int ABF_S = 72;
constexpr int V1_S  = 72;
constexpr int W_S   = 72;
constexpr int SC_S  = 17;

__device__ __forceinline__ unsigned short f2bf(float x) {
    // round-to-nearest-even fp32 -> bf16
    unsigned int u = __float_as_uint(x);
    u += 0x7FFFu + ((u >> 16) & 1u);
    return (unsigned short)(u >> 16);
}

__device__ __forceinline__ float fast_tanh(float x) {
    return 1.0f - 2.0f / (1.0f + __expf(2.0f * x));
}

__global__ __launch_bounds__(BLOCK) void attn_win_kernel(
    const float* __restrict__ A,   // (rows, 64)
    const float* __restrict__ W,   // (64, 64) row-major (out,in)
    const float* __restrict__ b,   // (64,)
    float* __restrict__ out,       // (rows, 64)
    int rows)
{
    __shared__ __align__(16) unsigned short Wbf[RANK][W_S];        //  9216 B
    __shared__ __align__(16) unsigned short Abf[4][32][ABF_S];     // 18432 B
    __shared__ __align__(16) unsigned short V1bf[4][TILE][V1_S];   //  9216 B
    __shared__ __align__(16) float          Sc[4][32][SC_S];       //  8704 B

    const int lane = threadIdx.x & 63;
    const int wv   = threadIdx.x >> 6;           // wave id 0..3
    const int m16  = lane & 15;
    const int quad = lane >> 4;
    const int r0   = blockIdx.x * TR;
    const int rw   = r0 + wv * TILE;             // this wave's output rows rw..rw+15

    // ---- Stage W (block-cooperative): fp32 -> bf16, packed uint2 writes ----
    {
        const int row = threadIdx.x >> 2;        // 0..63
        const int c0  = (threadIdx.x & 3) * 16;  // 16 elems per thread
        const float4* src = (const float4*)(W + row * RANK + c0);
        #pragma unroll
        for (int i = 0; i < 4; i++) {
            float4 v = src[i];
            unsigned int lo = (unsigned)f2bf(v.x) | ((unsigned)f2bf(v.y) << 16);
            unsigned int hi = (unsigned)f2bf(v.z) | ((unsigned)f2bf(v.w) << 16);
            *(uint2*)&Wbf[row][c0 + 4 * i] = make_uint2(lo, hi);
        }
    }

    // ---- Stage A window (per-wave): Abf[wv][i] = bf16(A[rw-5+i]), i=0..25 ----
    #pragma unroll 2
    for (int i = 0; i < 26; i++) {
        const int gr = rw - PAD + i;             // wave-uniform
        float v = 0.0f;
        if (gr >= 0 && gr < rows) v = A[(size_t)gr * RANK + lane];
        Abf[wv][i][lane] = f2bf(v);
    }
    #pragma unroll
    for (int i = 26; i < 32; i++) Abf[wv][i][lane] = 0;  // keep MFMA inputs finite

    __syncthreads();

    // ---- M1: V1 = tanh(A_rows(rw..rw+15) @ W^T + b) ----
    // a_frag: A[m=lane&15][k]  from Abf row 5+m ; b_frag: W[n=lane&15+16ct][k]
    float4v acc[4];
    #pragma unroll
    for (int ct = 0; ct < 4; ct++) {
        const float bv = b[ct * 16 + m16];       // bias folded into C operand
        acc[ct] = (float4v){bv, bv, bv, bv};
    }
    #pragma unroll
    for (int kf = 0; kf < 2; kf++) {
        const short8 af = *(const short8*)&Abf[wv][5 + m16][kf * 32 + quad * 8];
        #pragma unroll
        for (int ct = 0; ct < 4; ct++) {
            const short8 bfr = *(const short8*)&Wbf[ct * 16 + m16][kf * 32 + quad * 8];
            acc[ct] = __builtin_amdgcn_mfma_f32_16x16x32_bf16(af, bfr, acc[ct], 0, 0, 0);
        }
    }
    // epilogue: element (row q = quad*4+rg, col c = ct*16+m16) -> V1bf[q][c]
    #pragma unroll
    for (int ct = 0; ct < 4; ct++) {
        #pragma unroll
        for (int rg = 0; rg < 4; rg++) {
            const float t = fast_tanh(acc[ct][rg]);
            V1bf[wv][quad * 4 + rg][ct * 16 + m16] = f2bf(t);
        }
    }

    __syncthreads();

    // ---- M2: S[i][q] = dot(A[rw-5+i], v1[rw+q]),  i=0..31 (band uses 0..25) ----
    float4v sacc[2];
    sacc[0] = (float4v){0.f, 0.f, 0.f, 0.f};
    sacc[1] = (float4v){0.f, 0.f, 0.f, 0.f};
    #pragma unroll
    for (int kf = 0; kf < 2; kf++) {
        const short8 bfr = *(const short8*)&V1bf[wv][m16][kf * 32 + quad * 8];
        #pragma unroll
        for (int it = 0; it < 2; it++) {
            const short8 af = *(const short8*)&Abf[wv][it * 16 + m16][kf * 32 + quad * 8];
            sacc[it] = __builtin_amdgcn_mfma_f32_16x16x32_bf16(af, bfr, sacc[it], 0, 0, 0);
        }
    }
    // scatter S (C layout: i = it*16 + quad*4 + rg, q = m16) to LDS
    #pragma unroll
    for (int it = 0; it < 2; it++) {
        #pragma unroll
        for (int rg = 0; rg < 4; rg++)
            Sc[wv][it * 16 + quad * 4 + rg][m16] = sacc[it][rg];
    }

    __syncthreads();

    // ---- softmax over the 11-row band of column q = m16 ----
    // All 4 quads compute the same q redundantly (LDS broadcast reads, no
    // divergence); lane rr (0..15) ends up holding row rw+rr's probs.
    float p[WINDOW];
    {
        float s[WINDOW];
        float mx = -1e30f;
        #pragma unroll
        for (int w = 0; w < WINDOW; w++) {
            s[w] = Sc[wv][m16 + w][m16];         // i = q + w
            mx = fmaxf(mx, s[w]);
        }
        float den = 0.0f;
        #pragma unroll
        for (int w = 0; w < WINDOW; w++) {
            p[w] = __expf((s[w] - mx) * 0.125f); // 1/sqrt(64) folded here
            den += p[w];
        }
        const float rden = __fdividef(1.0f, den);
        #pragma unroll
        for (int w = 0; w < WINDOW; w++) p[w] *= rden;
    }

    // ---- P4: out[rw+rr] = sum_w p[rr][w] * A[rw+rr-5+w]  (rolling regs) ----
    float aw[16];   // circular: slot s&15 holds A[rw-5+s][lane]
    #pragma unroll
    for (int s = 0; s < WINDOW; s++) {
        const int gr = rw - PAD + s;
        aw[s] = (gr >= 0 && gr < rows) ? A[(size_t)gr * RANK + lane] : 0.0f;
    }
    #pragma unroll
    for (int rr = 0; rr < TILE; rr++) {
        float o = 0.0f;
        #pragma unroll
        for (int w = 0; w < WINDOW; w++) {
            const float pw = __uint_as_float(
                __builtin_amdgcn_readlane(__float_as_uint(p[w]), rr));
            o = fmaf(pw, aw[(rr + w) & 15], o);
        }
        if (rw + rr < rows) out[(size_t)(rw + rr) * RANK + lane] = o;
        if (rr < TILE - 1) {
            const int s  = rr + WINDOW;          // next row needed: rw-5+s
            const int gr = rw - PAD + s;
            aw[s & 15] = (gr >= 0 && gr < rows) ? A[(size_t)gr * RANK + lane] : 0.0f;
        }
    }
}

extern "C" void kernel_launch(void* const* d_in, const int* in_sizes, int n_in,
                              void* d_out, int out_size, void* d_ws, size_t ws_size,
                              hipStream_t stream) {
    const float* A = (const float*)d_in[0];
    const float* W = (const float*)d_in[1];
    const float* b = (const float*)d_in[2];
    float* out = (float*)d_out;

    const int rows   = in_sizes[0] / RANK;
    const int blocks = (rows + TR - 1) / TR;

    hipLaunchKernelGGL(attn_win_kernel, dim3(blocks), dim3(BLOCK), 0, stream,
                       A, W, b, out, rows);
}

// Round 3
// 135.622 us; speedup vs baseline: 1.9870x; 1.2374x over previous
//
#include <hip/hip_runtime.h>
#include <hip/hip_bf16.h>

// Windowed attention smoothing via MFMA — barrier-free, per-wave autonomous.
// rows=200000, RANK=64, WINDOW=11. Block=256 (4 waves), 16 rows/wave/tile,
// persistent grid-stride loop over 64-row block-tiles.
//
// Per wave tile (rows rw..rw+15):
//   - A fragments (M1 rows + 32-row band) loaded DIRECTLY from global fp32,
//     converted to bf16 in regs (no LDS staging, no barriers, all loads in flight)
//   - M1: V1 = tanh(A@W^T + b)   8x mfma_16x16x32_bf16, W frags persistent in VGPRs
//   - V1 -> per-wave LDS (B-frag relayout for M2)
//   - M2: banded scores S = Aband@V1^T   4x mfma -> per-wave LDS scatter
//   - softmax over 11-band per column (LDS broadcast reads, redundant per quad)
//   - P4: out = P·window in fp32 VALU, probs broadcast via static v_readlane
// No __syncthreads anywhere: LDS regions are wave-private; DS pipe is in-order
// within a wave.

constexpr int RANK   = 64;
constexpr int WINDOW = 11;
constexpr int PAD    = 5;
constexpr int TILE   = 16;   // rows per wave
constexpr int BLOCK  = 256;  // 4 waves
constexpr int TR     = 64;   // rows per block-tile

typedef short short8  __attribute__((ext_vector_type(8)));
typedef float float4v __attribute__((ext_vector_type(4)));

constexpr int V1_S = 72;  // bf16 elems per V1 row (144B, 16B-aligned)
constexpr int SC_S = 18;  // f32 elems per Sc row (breaks pow2, writes <=2-way)

__device__ __forceinline__ short8 cvt_bf8(float4 a, float4 b) {
    union { short8 s; __hip_bfloat162 h[4]; } u;
    u.h[0] = __float22bfloat162_rn(make_float2(a.x, a.y));
    u.h[1] = __float22bfloat162_rn(make_float2(a.z, a.w));
    u.h[2] = __float22bfloat162_rn(make_float2(b.x, b.y));
    u.h[3] = __float22bfloat162_rn(make_float2(b.z, b.w));
    return u.s;
}

// Load one MFMA A-fragment half (8 cols) of a global fp32 row, bf16-convert.
__device__ __forceinline__ short8 load_afrag(const float* __restrict__ A,
                                             int row, int col0, int rows) {
    if ((unsigned)row < (unsigned)rows) {
        const float4* p = (const float4*)(A + (size_t)row * RANK + col0);
        return cvt_bf8(p[0], p[1]);
    }
    return (short8)0;   // zero-pad rows (matches jnp.pad semantics: score 0)
}

__device__ __forceinline__ float fast_tanh(float x) {
    return 1.0f - 2.0f / (1.0f + __expf(2.0f * x));
}

__global__ __launch_bounds__(BLOCK, 4) void attn_win_kernel(
    const float* __restrict__ A,   // (rows, 64)
    const float* __restrict__ W,   // (64, 64) row-major (out,in)
    const float* __restrict__ b,   // (64,)
    float* __restrict__ out,       // (rows, 64)
    int rows)
{
    __shared__ __align__(16) __hip_bfloat16 V1[4][TILE][V1_S];  // 9216 B
    __shared__ __align__(16) float          Sc[4][32][SC_S];    // 9216 B

    const int lane = threadIdx.x & 63;
    const int wv   = threadIdx.x >> 6;
    const int m16  = lane & 15;
    const int quad = lane >> 4;

    // ---- Persistent W fragments (32 VGPRs) + bias, converted ONCE per wave ----
    short8 wfrag[4][2];  // [ct][kf]: W[n=ct*16+m16][kf*32 + quad*8 + j]
    #pragma unroll
    for (int ct = 0; ct < 4; ct++) {
        #pragma unroll
        for (int kf = 0; kf < 2; kf++) {
            const float4* p =
                (const float4*)(W + (ct * 16 + m16) * RANK + kf * 32 + quad * 8);
            wfrag[ct][kf] = cvt_bf8(p[0], p[1]);
        }
    }
    float bias[4];
    #pragma unroll
    for (int ct = 0; ct < 4; ct++) bias[ct] = b[ct * 16 + m16];

    const int n_btiles = (rows + TR - 1) / TR;
    for (int bt = blockIdx.x; bt < n_btiles; bt += gridDim.x) {
        const int rw = bt * TR + wv * TILE;   // this wave's rows rw..rw+15

        // ---- fragment loads, all independent & in flight ----
        short8 abnd[2][2];  // band rows rw-5+it*16+m16 (band idx i=it*16+m16)
        short8 am1[2];      // M1 rows rw+m16
        #pragma unroll
        for (int it = 0; it < 2; it++)
            #pragma unroll
            for (int kf = 0; kf < 2; kf++)
                abnd[it][kf] = load_afrag(A, rw - PAD + it * 16 + m16,
                                          kf * 32 + quad * 8, rows);
        #pragma unroll
        for (int kf = 0; kf < 2; kf++)
            am1[kf] = load_afrag(A, rw + m16, kf * 32 + quad * 8, rows);

        // ---- M1: V1 = tanh(A[rw..rw+15] @ W^T + b) ----
        float4v acc[4];
        #pragma unroll
        for (int ct = 0; ct < 4; ct++)
            acc[ct] = (float4v){bias[ct], bias[ct], bias[ct], bias[ct]};
        #pragma unroll
        for (int kf = 0; kf < 2; kf++)
            #pragma unroll
            for (int ct = 0; ct < 4; ct++)
                acc[ct] = __builtin_amdgcn_mfma_f32_16x16x32_bf16(
                    am1[kf], wfrag[ct][kf], acc[ct], 0, 0, 0);
        // epilogue: element (row q=quad*4+rg, col c=ct*16+m16) -> V1[q][c]
        #pragma unroll
        for (int ct = 0; ct < 4; ct++)
            #pragma unroll
            for (int rg = 0; rg < 4; rg++)
                V1[wv][quad * 4 + rg][ct * 16 + m16] =
                    __float2bfloat16(fast_tanh(acc[ct][rg]));

        // ---- M2: S[i][q] = dot(Aband[i], v1[q]) ----
        float4v sacc[2];
        sacc[0] = (float4v){0.f, 0.f, 0.f, 0.f};
        sacc[1] = (float4v){0.f, 0.f, 0.f, 0.f};
        #pragma unroll
        for (int kf = 0; kf < 2; kf++) {
            const short8 bfr =
                *(const short8*)&V1[wv][m16][kf * 32 + quad * 8];
            #pragma unroll
            for (int it = 0; it < 2; it++)
                sacc[it] = __builtin_amdgcn_mfma_f32_16x16x32_bf16(
                    abnd[it][kf], bfr, sacc[it], 0, 0, 0);
        }
        // scatter S (i = it*16+quad*4+rg, q = m16); rows 26..31 are dead
        #pragma unroll
        for (int it = 0; it < 2; it++)
            #pragma unroll
            for (int rg = 0; rg < 4; rg++)
                Sc[wv][it * 16 + quad * 4 + rg][m16] = sacc[it][rg];

        // ---- softmax over band i in [q, q+10] of column q=m16 ----
        // (redundant across quads; broadcast LDS reads; lane rr holds row rw+rr's p)
        float p[WINDOW];
        {
            float s[WINDOW];
            float mx = -1e30f;
            #pragma unroll
            for (int w = 0; w < WINDOW; w++) {
                s[w] = Sc[wv][m16 + w][m16];
                mx = fmaxf(mx, s[w]);
            }
            float den = 0.0f;
            #pragma unroll
            for (int w = 0; w < WINDOW; w++) {
                p[w] = __expf((s[w] - mx) * 0.125f);  // 1/sqrt(64) folded in
                den += p[w];
            }
            const float rden = __fdividef(1.0f, den);
            #pragma unroll
            for (int w = 0; w < WINDOW; w++) p[w] *= rden;
        }

        // ---- P4: out[rw+rr][lane] = sum_w p[rr][w] * A[rw+rr-5+w][lane] ----
        float aw[26];  // fp32 window, coalesced dword loads, uniform guards
        #pragma unroll
        for (int s = 0; s < 26; s++) {
            const int gr = rw - PAD + s;
            aw[s] = ((unsigned)gr < (unsigned)rows)
                        ? A[(size_t)gr * RANK + lane] : 0.0f;
        }
        #pragma unroll
        for (int rr = 0; rr < TILE; rr++) {
            float o = 0.0f;
            #pragma unroll
            for (int w = 0; w < WINDOW; w++) {
                const float pw = __uint_as_float(
                    __builtin_amdgcn_readlane(__float_as_uint(p[w]), rr));
                o = fmaf(pw, aw[rr + w], o);
            }
            if (rw + rr < rows)
                out[(size_t)(rw + rr) * RANK + lane] = o;
        }
    }
}

extern "C" void kernel_launch(void* const* d_in, const int* in_sizes, int n_in,
                              void* d_out, int out_size, void* d_ws, size_t ws_size,
                              hipStream_t stream) {
    const float* A = (const float*)d_in[0];
    const float* W = (const float*)d_in[1];
    const float* b = (const float*)d_in[2];
    float* out = (float*)d_out;

    const int rows     = in_sizes[0] / RANK;
    const int n_btiles = (rows + TR - 1) / TR;
    const int blocks   = n_btiles < 1024 ? n_btiles : 1024;  // persistent

    hipLaunchKernelGGL(attn_win_kernel, dim3(blocks), dim3(BLOCK), 0, stream,
                       A, W, b, out, rows);
}